// Round 1
// baseline (535.509 us; speedup 1.0000x reference)
//
#include <hip/hip_runtime.h>
#include <cstdint>
#include <cstddef>

#define DDIM 4096          // hidden dim
#define D4   (DDIM / 4)    // float4 per row = 1024
#define NE   16            // experts
#define TPB_B 1024         // pass-B block size

// ---------------------------------------------------------------------------
// Pass A: logits GEMV + bias + top-2 softmax renorm + dispatch tensor.
// One wave = 8 tokens. lane = tg*16 + kl : tg in [0,4) picks a 2-token pair,
// kl in [0,16) picks the K-slice (float4 index = kl + 16*i, i in [0,64)).
// acc: 2 tokens x 16 experts per lane -> reduce over the 16 kl lanes.
// ---------------------------------------------------------------------------
__global__ __launch_bounds__(256, 4) void router_pass_a(
    const float* __restrict__ x, const float* __restrict__ W,
    const float* __restrict__ b, float* __restrict__ out, int T)
{
    const int wave = (int)((blockIdx.x * blockDim.x + threadIdx.x) >> 6);
    const int lane = (int)(threadIdx.x & 63);
    const int tg   = lane >> 4;     // 0..3
    const int kl   = lane & 15;     // 0..15
    const int tok  = wave * 8 + tg * 2;   // this lane-group's two tokens

    const float4* __restrict__ x4 = (const float4*)x;
    const float4* __restrict__ W4 = (const float4*)W;
    const float4* xr0 = x4 + (size_t)tok * D4;
    const float4* xr1 = xr0 + D4;

    float acc0[NE], acc1[NE];
#pragma unroll
    for (int e = 0; e < NE; ++e) { acc0[e] = 0.f; acc1[e] = 0.f; }

#pragma unroll 2
    for (int i = 0; i < 64; ++i) {
        const int f4 = kl + (i << 4);
        float4 a0 = xr0[f4];
        float4 a1 = xr1[f4];
#pragma unroll
        for (int e = 0; e < NE; ++e) {
            float4 w = W4[(size_t)e * D4 + f4];
            acc0[e] += a0.x * w.x + a0.y * w.y + a0.z * w.z + a0.w * w.w;
            acc1[e] += a1.x * w.x + a1.y * w.y + a1.z * w.z + a1.w * w.w;
        }
    }

    // reduce across the 16 kl-lanes of this group (xor masks 1,2,4,8 stay in-group)
#pragma unroll
    for (int m = 1; m <= 8; m <<= 1) {
#pragma unroll
        for (int e = 0; e < NE; ++e) {
            acc0[e] += __shfl_xor(acc0[e], m, 64);
            acc1[e] += __shfl_xor(acc1[e], m, 64);
        }
    }

    // biased logits (every lane of the group now holds all 16 for both tokens)
    float l0[NE], l1[NE];
#pragma unroll
    for (int e = 0; e < NE; ++e) {
        float be = b[e];
        l0[e] = acc0[e] + be;
        l1[e] = acc1[e] + be;
    }

    // write logits: lane kl writes expert kl for both tokens (coalesced 256B/group)
    out[(size_t)tok * NE + kl]       = l0[kl];
    out[(size_t)(tok + 1) * NE + kl] = l1[kl];

    float* __restrict__ disp = out + (size_t)T * NE;

    // token 0 of the pair
    {
        int i1 = 0; float m1 = l0[0];
#pragma unroll
        for (int e = 1; e < NE; ++e) if (l0[e] > m1) { m1 = l0[e]; i1 = e; }
        int i2 = -1; float m2 = -__builtin_inff();
#pragma unroll
        for (int e = 0; e < NE; ++e) if (e != i1 && l0[e] > m2) { m2 = l0[e]; i2 = e; }
        float q  = expf(m2 - m1);        // p2/p1
        float r1 = 1.f / (1.f + q);
        float r2 = q / (1.f + q);
        disp[(size_t)tok * NE + kl] = (kl == i1) ? r1 : ((kl == i2) ? r2 : 0.f);
    }
    // token 1 of the pair
    {
        int i1 = 0; float m1 = l1[0];
#pragma unroll
        for (int e = 1; e < NE; ++e) if (l1[e] > m1) { m1 = l1[e]; i1 = e; }
        int i2 = -1; float m2 = -__builtin_inff();
#pragma unroll
        for (int e = 0; e < NE; ++e) if (e != i1 && l1[e] > m2) { m2 = l1[e]; i2 = e; }
        float q  = expf(m2 - m1);
        float r1 = 1.f / (1.f + q);
        float r2 = q / (1.f + q);
        disp[(size_t)(tok + 1) * NE + kl] = (kl == i1) ? r1 : ((kl == i2) ? r2 : 0.f);
    }
}

// ---------------------------------------------------------------------------
// Pass B: per-expert stable compaction of token ids (dispatch > 0), -1 padded.
// One block per expert; ballot + popcount wave prefix, LDS cross-wave scan.
// ---------------------------------------------------------------------------
__global__ __launch_bounds__(TPB_B) void router_pass_b(
    const float* __restrict__ disp, float* __restrict__ idxout, int T)
{
    const int e    = (int)blockIdx.x;
    const int tid  = (int)threadIdx.x;
    const int lane = tid & 63;
    const int wid  = tid >> 6;              // 0..15
    __shared__ int wtot[TPB_B / 64];

    float* __restrict__ row = idxout + (size_t)e * T;
    int off = 0;

    const int iters = T / TPB_B;
    for (int it = 0; it < iters; ++it) {
        int t = it * TPB_B + tid;
        bool flag = disp[(size_t)t * NE + e] > 0.0f;
        unsigned long long bal = __ballot(flag ? 1 : 0);
        int lpfx = __popcll(bal & ((1ull << lane) - 1ull));
        if (lane == 0) wtot[wid] = __popcll(bal);
        __syncthreads();
        int wpfx = 0;
        for (int w = 0; w < wid; ++w) wpfx += wtot[w];
        int btot = wpfx;
        for (int w = wid; w < TPB_B / 64; ++w) btot += wtot[w];
        if (flag) row[off + wpfx + lpfx] = (float)t;
        off += btot;
        __syncthreads();   // protect wtot before next iteration overwrites
    }
    // -1 tail fill
    for (int j = off + tid; j < T; j += TPB_B) row[j] = -1.0f;
}

extern "C" void kernel_launch(void* const* d_in, const int* in_sizes, int n_in,
                              void* d_out, int out_size, void* d_ws, size_t ws_size,
                              hipStream_t stream)
{
    const float* x = (const float*)d_in[0];
    const float* W = (const float*)d_in[1];
    const float* b = (const float*)d_in[2];
    float* out = (float*)d_out;

    const int T = in_sizes[0] / DDIM;      // 16384 tokens

    // Pass A: one wave per 8 tokens -> T/8 waves -> T/32 blocks of 256
    const int blocksA = T / 32;
    router_pass_a<<<blocksA, 256, 0, stream>>>(x, W, b, out, T);

    // Pass B: 16 blocks (one per expert)
    const float* disp = out + (size_t)T * NE;
    float* idxout = out + (size_t)2 * T * NE;
    router_pass_b<<<NE, TPB_B, 0, stream>>>(disp, idxout, T);
}

// Round 2
// 393.365 us; speedup vs baseline: 1.3614x; 1.3614x over previous
//
#include <hip/hip_runtime.h>
#include <cstdint>
#include <cstddef>

#define DDIM 4096          // hidden dim
#define D4   (DDIM / 4)    // float4 per row = 1024
#define NE   16            // experts
#define CHUNK 256          // pass-B tokens per block

// ---------------------------------------------------------------------------
// Pass A: logits GEMV + bias + top-2 softmax renorm + dispatch tensor +
// packed per-token expert-pair byte for pass B.
// One wave = 4 tokens; K split across all 64 lanes (float4 idx = lane + 64*i).
// acc[j], j = t*16+e. Split-exchange butterfly leaves the full sum for
// (t = lane>>4, e = lane&15) in acc[0] -> coalesced epilogue.
// ---------------------------------------------------------------------------
__global__ __launch_bounds__(256, 4) void router_pass_a(
    const float* __restrict__ x, const float* __restrict__ W,
    const float* __restrict__ b, float* __restrict__ out,
    unsigned char* __restrict__ packed, int T)
{
    const int wave = (int)((blockIdx.x * blockDim.x + threadIdx.x) >> 6);
    const int lane = (int)(threadIdx.x & 63);
    const int tok0 = wave * 4;

    const float4* __restrict__ x4 = (const float4*)x;
    const float4* __restrict__ W4 = (const float4*)W;
    const float4* xr = x4 + (size_t)tok0 * D4;

    float acc[64];
#pragma unroll
    for (int j = 0; j < 64; ++j) acc[j] = 0.f;

    for (int i = 0; i < 16; ++i) {
        const int f4 = lane + (i << 6);
        float4 a0 = xr[f4];
        float4 a1 = xr[f4 + D4];
        float4 a2 = xr[f4 + 2 * D4];
        float4 a3 = xr[f4 + 3 * D4];
#pragma unroll
        for (int e = 0; e < NE; ++e) {
            float4 w = W4[(size_t)e * D4 + f4];
            acc[e]      += a0.x * w.x + a0.y * w.y + a0.z * w.z + a0.w * w.w;
            acc[16 + e] += a1.x * w.x + a1.y * w.y + a1.z * w.z + a1.w * w.w;
            acc[32 + e] += a2.x * w.x + a2.y * w.y + a2.z * w.z + a2.w * w.w;
            acc[48 + e] += a3.x * w.x + a3.y * w.y + a3.z * w.z + a3.w * w.w;
        }
    }

    // split-exchange reduction: after all stages, acc[0] holds the full sum
    // for index j == lane (t = lane>>4, e = lane&15).
#pragma unroll
    for (int m = 32; m >= 1; m >>= 1) {
        const bool hi = (lane & m) != 0;
#pragma unroll
        for (int i = 0; i < m; ++i) {
            float send = hi ? acc[i] : acc[i + m];
            float keep = hi ? acc[i + m] : acc[i];
            acc[i] = keep + __shfl_xor(send, m, 64);
        }
    }

    const int e = lane & 15;
    const float logit = acc[0] + b[e];
    out[(size_t)tok0 * NE + lane] = logit;   // 64 consecutive floats per wave

    // top-2 (value, index) merge across the 16-lane group; lower index wins ties
    float m1 = logit; int i1 = e;
    float m2 = -__builtin_inff(); int i2 = NE;
#pragma unroll
    for (int m = 1; m <= 8; m <<= 1) {
        float om1 = __shfl_xor(m1, m, 64); int oi1 = __shfl_xor(i1, m, 64);
        float om2 = __shfl_xor(m2, m, 64); int oi2 = __shfl_xor(i2, m, 64);
        bool aFirst = (m1 > om1) || (m1 == om1 && i1 < oi1);
        float n1v = aFirst ? m1 : om1;  int n1i = aFirst ? i1 : oi1;
        float l1v = aFirst ? om1 : m1;  int l1i = aFirst ? oi1 : i1;  // loser of firsts
        float c2v = aFirst ? m2 : om2;  int c2i = aFirst ? i2 : oi2;  // winner's 2nd
        bool s = (l1v > c2v) || (l1v == c2v && l1i < c2i);
        m1 = n1v; i1 = n1i;
        m2 = s ? l1v : c2v; i2 = s ? l1i : c2i;
    }

    const float q  = expf(m2 - m1);          // p2/p1
    const float r1 = 1.f / (1.f + q);
    const float r2 = q / (1.f + q);
    float* __restrict__ disp = out + (size_t)T * NE;
    disp[(size_t)tok0 * NE + lane] = (e == i1) ? r1 : ((e == i2) ? r2 : 0.f);

    if (e == 0)
        packed[tok0 + (lane >> 4)] = (unsigned char)(i1 | (i2 << 4));
}

// ---------------------------------------------------------------------------
// Pass B1: per-chunk expert histogram + fill expert_indices rows with -1.
// ---------------------------------------------------------------------------
__global__ __launch_bounds__(CHUNK) void router_count_fill(
    const unsigned char* __restrict__ packed, int* __restrict__ gcounts,
    float* __restrict__ idxout, int T)
{
    const int c = (int)blockIdx.x;
    const int tid = (int)threadIdx.x;
    __shared__ int cnt[NE];
    if (tid < NE) cnt[tid] = 0;
    __syncthreads();

    const int t = c * CHUNK + tid;
    const unsigned p = packed[t];
    atomicAdd(&cnt[p & 15], 1);
    atomicAdd(&cnt[p >> 4], 1);

#pragma unroll
    for (int ee = 0; ee < NE; ++ee)
        idxout[(size_t)ee * T + t] = -1.0f;

    __syncthreads();
    if (tid < NE) gcounts[c * NE + tid] = cnt[tid];
}

// ---------------------------------------------------------------------------
// Pass B2: exclusive prefix over 64 chunks per expert. 16 waves, wave=expert,
// lane=chunk. Requires T/CHUNK == 64.
// ---------------------------------------------------------------------------
__global__ __launch_bounds__(1024) void router_scan(
    const int* __restrict__ gcounts, int* __restrict__ goffs)
{
    const int e = (int)(threadIdx.x >> 6);
    const int c = (int)(threadIdx.x & 63);
    int v = gcounts[c * NE + e];
    const int own = v;
#pragma unroll
    for (int sh = 1; sh < 64; sh <<= 1) {
        int t = __shfl_up(v, sh, 64);
        if (c >= sh) v += t;
    }
    goffs[c * NE + e] = v - own;
}

// ---------------------------------------------------------------------------
// Pass B3: stable scatter of token ids into expert rows.
// ---------------------------------------------------------------------------
__global__ __launch_bounds__(CHUNK) void router_scatter(
    const unsigned char* __restrict__ packed, const int* __restrict__ goffs,
    float* __restrict__ idxout, int T)
{
    const int c = (int)blockIdx.x;
    const int tid = (int)threadIdx.x;
    const int lane = tid & 63;
    const int wid = tid >> 6;               // 0..3
    __shared__ int wtot[CHUNK / 64][NE];

    const int t = c * CHUNK + tid;
    const unsigned p = packed[t];
    const int e1 = (int)(p & 15);
    const int e2 = (int)(p >> 4);

    unsigned long long bal[NE];
#pragma unroll
    for (int ee = 0; ee < NE; ++ee)
        bal[ee] = __ballot((e1 == ee) || (e2 == ee));

    if (lane < NE) wtot[wid][lane] = __popcll(bal[lane]);
    __syncthreads();

    const unsigned long long lt = (1ull << lane) - 1ull;
    int r1 = __popcll(bal[e1] & lt);
    int r2 = __popcll(bal[e2] & lt);
    for (int w = 0; w < wid; ++w) { r1 += wtot[w][e1]; r2 += wtot[w][e2]; }

    idxout[(size_t)e1 * T + goffs[c * NE + e1] + r1] = (float)t;
    idxout[(size_t)e2 * T + goffs[c * NE + e2] + r2] = (float)t;
}

extern "C" void kernel_launch(void* const* d_in, const int* in_sizes, int n_in,
                              void* d_out, int out_size, void* d_ws, size_t ws_size,
                              hipStream_t stream)
{
    const float* x = (const float*)d_in[0];
    const float* W = (const float*)d_in[1];
    const float* b = (const float*)d_in[2];
    float* out = (float*)d_out;

    const int T = in_sizes[0] / DDIM;       // 16384 tokens

    unsigned char* packed = (unsigned char*)d_ws;
    int* gcounts = (int*)((char*)d_ws + ((size_t)T + 255 & ~(size_t)255));
    int* goffs   = gcounts + (T / CHUNK) * NE;

    float* idxout = out + (size_t)2 * T * NE;

    // Pass A: one wave per 4 tokens -> T/4 waves -> T/16 blocks of 256
    router_pass_a<<<T / 16, 256, 0, stream>>>(x, W, b, out, packed, T);

    // Pass B: count+fill, scan, scatter
    router_count_fill<<<T / CHUNK, CHUNK, 0, stream>>>(packed, gcounts, idxout, T);
    router_scan<<<1, 1024, 0, stream>>>(gcounts, goffs);
    router_scatter<<<T / CHUNK, CHUNK, 0, stream>>>(packed, goffs, idxout, T);
}